// Round 10
// baseline (2868.820 us; speedup 1.0000x reference)
//
#include <hip/hip_runtime.h>
#include <hip/hip_fp16.h>

typedef unsigned int u32;

// Soft-DTW fwd, T=4096, D=16, gamma=1. fp32 DP, log2 domain, carried as an
// unnormalized logsumexp pair (m,w): R' = m - log2(w). Cell:
// mu = min3(m_u,m_d,m_l); w' = sum w_t*2^(mu-m_t); m' = d' + mu. Fold every
// 4 groups. 16 blocks x 4 waves x 64 lanes, 1 row/lane, 1 wave/SIMD.
// R10 KEY CHANGE: the 8-step inner body is BRANCHLESS — publishes are
// unconditional LDS+global stores to cndmask-selected addresses (real ring
// slot for the producer lane, per-lane trash otherwise). No exec-mask
// save/restore per step -> the scheduler can software-pipeline off-chain
// work (exp2/fma/log2) across steps instead of paying full latency serially
// (R4..R9 all plateaued at ~330 cyc/step due to per-step exec dances).
// Handoff: full-row single-write rings, sentinel 0xFFFFFFFF; LDS intra-block,
// global (relaxed agent atomics — R7/R8: plain stores break cross-XCD
// visibility) inter-block. Block0-wave0 polls a BIG-prefilled LDS stub.
// Poll prefetch 2 groups (batched re-poll fallback), Et prefetch 4 groups.

constexpr int   kN      = 4096;
constexpr int   kLanes  = 64;
constexpr int   kWaves  = 4;
constexpr int   kBlocks = 16;
constexpr int   kSMax   = kN + kLanes;     // 4160
constexpr int   kG      = 8;
constexpr int   kGroups = kSMax / kG;      // 520
constexpr u32   kSent   = 0xFFFFFFFFu;
constexpr float kBigP   = 1.4426950408889634e10f;   // 1e10 * log2e
constexpr float kLog2e  = 1.4426950408889634f;
constexpr float kLn2    = 0.6931471805599453f;
constexpr int   kRS     = 4104;            // ring stride (u32), LDS and global
constexpr int   kGRTot  = (kBlocks - 1) * kRS;          // 61560
constexpr int   kGTrash = kGRTot;                       // + gw*64 + l
constexpr int   kGRingEnd = kGRTot + kBlocks * kWaves * kLanes;   // 65656
constexpr int   kLTrash = 3 * kRS;                      // + v*64 + l
constexpr int   kLBig   = kLTrash + kWaves * kLanes;    // 8 BIG entries
constexpr int   kLdsTot = kLBig + kG;                   // 12576 u32 = 50.3 KB

#if __has_builtin(__builtin_amdgcn_exp2f)
#define EXP2F(x) __builtin_amdgcn_exp2f(x)
#else
#define EXP2F(x) exp2f(x)
#endif
#if __has_builtin(__builtin_amdgcn_logf)
#define LOG2F(x) __builtin_amdgcn_logf(x)
#else
#define LOG2F(x) log2f(x)
#endif

__device__ __forceinline__ float dppShr1f(float v) {
  // wf_sr1: lane l <- lane l-1; lane 0 keeps old(=0), overwritten by cndmask
  return __int_as_float(__builtin_amdgcn_update_dpp(0, __float_as_int(v), 0x138, 0xF, 0xF, false));
}
__device__ __forceinline__ u32 aloadG(const u32* p) {
  return __hip_atomic_load(p, __ATOMIC_RELAXED, __HIP_MEMORY_SCOPE_AGENT);
}
__device__ __forceinline__ void astoreG(u32* p, u32 v) {
  __hip_atomic_store(p, v, __ATOMIC_RELAXED, __HIP_MEMORY_SCOPE_AGENT);
}
__device__ __forceinline__ u32 aloadL(const u32* p) {
  return __hip_atomic_load(p, __ATOMIC_RELAXED, __HIP_MEMORY_SCOPE_WORKGROUP);
}
__device__ __forceinline__ void astoreL(u32* p, u32 v) {
  __hip_atomic_store(p, v, __ATOMIC_RELAXED, __HIP_MEMORY_SCOPE_WORKGROUP);
}
__device__ __forceinline__ u32 max8(const u32 (&c)[kG]) {
  u32 m = c[0];
#pragma unroll
  for (int q = 1; q < kG; ++q) m = m > c[q] ? m : c[q];
  return m;
}

__global__ __launch_bounds__(256) void sdtw_prep(const float* __restrict__ A,
                                                 const float* __restrict__ B,
                                                 uint4* __restrict__ Et,
                                                 u32* __restrict__ gring) {
  const int tid = threadIdx.x;
  const int w   = blockIdx.y;                         // band 0..63
  const int gid = ((w * (int)gridDim.x + (int)blockIdx.x) << 8) + tid;
  if (gid < kGRTot) gring[gid] = kSent;

  const int l   = tid & 63;
  const int grp = (int)blockIdx.x * 4 + (tid >> 6);

  const float4* Ap = (const float4*)(A + (size_t)(w * 64 + l) * 16);
  const float4 a0 = Ap[0], a1 = Ap[1], a2 = Ap[2], a3 = Ap[3];
  auto sq = [](float4 a, float4 b) {
    const float dx = a.x - b.x, dy = a.y - b.y, dz = a.z - b.z, dw = a.w - b.w;
    return fmaf(dx, dx, fmaf(dy, dy, fmaf(dz, dz, dw * dw)));
  };
  u32 hp[4];
#pragma unroll
  for (int pr = 0; pr < 4; ++pr) {
    float dv[2];
#pragma unroll
    for (int h = 0; h < 2; ++h) {
      const int q = pr * 2 + h;
      const int s = grp * kG + q + 1;
      const int jb = min(max(s - l - 1, 0), kN - 1);
      const float4* Bp = (const float4*)(B + (size_t)jb * 16);
      dv[h] = (sq(a0, Bp[0]) + sq(a1, Bp[1]) + sq(a2, Bp[2]) + sq(a3, Bp[3])) * kLog2e;
    }
    hp[pr] = ((u32)__half_as_ushort(__float2half(dv[1])) << 16)
           |  (u32)__half_as_ushort(__float2half(dv[0]));
  }
  Et[((size_t)w * kGroups + grp) * 64 + l] = make_uint4(hp[0], hp[1], hp[2], hp[3]);
}

// MODE: 0 = prologue (mask cells, verify on, publish only e>=0),
//       1 = main (branchless), 2 = epilogue (mask, no verify, out write)
template <int MODE>
__device__ __forceinline__ void run(
    int gBeg, int gEnd, int l, int v, int b, int gw,
    const uint4* __restrict__ EtL, u32* ring, u32* __restrict__ gring,
    bool consG, bool dummy, bool selL, bool selG,
    int pollIdx, const u32* __restrict__ gin,
    float& mp, float& wp, float& mdm, float& wdm,
    u32 (&c)[2][kG], uint4 (&e4)[4], float* __restrict__ out) {
  const bool isL0 = (l == 0);
  for (int g = gBeg; g < gEnd; ++g) {
    const int ri = g & 1, ei = g & 3;

    // ---- consume/verify poll slots for this group (prefetched 2 ago) ----
    if (MODE != 2) {
      u32 mm = max8(c[ri]);
      if (__builtin_expect(mm == kSent, 0)) {
        const int eb = g * kG;
        do {
          if (consG) {
#pragma unroll
            for (int q = 0; q < kG; ++q) c[ri][q] = aloadG(gin + eb + q);
          } else {
#pragma unroll
            for (int q = 0; q < kG; ++q) c[ri][q] = aloadL(ring + pollIdx + eb + q);
          }
          mm = max8(c[ri]);
        } while (mm == kSent);
      }
    }

    // ---- per-group publish bases (cndmask-selected: real vs per-lane trash)
    const u32 lb = selL ? (u32)(v * kRS + g * kG - 63) : (u32)(kLTrash + v * kLanes + l);
    const u32 gb = selG ? (u32)(b * kRS + g * kG - 63) : (u32)(kGTrash + gw * kLanes + l);

    // ---- 8 branchless cells ----
    const u32 ecs[4] = {e4[ei].x, e4[ei].y, e4[ei].z, e4[ei].w};
#pragma unroll
    for (int q = 0; q < kG; ++q) {
      const int s = g * kG + q + 1;
      float um = dppShr1f(mp);
      float wu = dppShr1f(wp);
      um = isL0 ? __uint_as_float(c[ri][q]) : um;
      wu = isL0 ? 1.0f : wu;

      u32 hw = ecs[q >> 1];
      if (q & 1) hw >>= 16;
      const float dpv = __half2float(__ushort_as_half((unsigned short)(hw & 0xFFFFu)));

      const float mu = fminf(fminf(um, mdm), mp);       // v_min3
      const float pu = EXP2F(mu - um);
      const float pd = EXP2F(mu - mdm);
      const float pl = EXP2F(mu - mp);
      float wn = fmaf(wu, pu, fmaf(wdm, pd, wp * pl));
      float mn = dpv + mu;
      if (MODE == 0) { const bool jv = s > l;            mn = jv ? mn : kBigP; wn = jv ? wn : 1.0f; }
      if (MODE == 2) { const bool jv = (s - l) <= kN;    mn = jv ? mn : kBigP; wn = jv ? wn : 1.0f; }
      mdm = um; wdm = wu;
      mp = mn; wp = wn;

      const float r  = mn - LOG2F(wn);                   // folded value (off-chain)
      const u32   rb = __float_as_uint(r);
      if (MODE == 0) {
        // only s >= 64 produces a real entry (e = s-64 >= 0)
        const bool okL = selL && (s >= kLanes);
        const bool okG = selG && (s >= kLanes);
        const u32 lb2 = okL ? (u32)(v * kRS + s - kLanes) : (u32)(kLTrash + v * kLanes + l);
        const u32 gb2 = okG ? (u32)(b * kRS + s - kLanes) : (u32)(kGTrash + gw * kLanes + l);
        astoreL(ring + lb2, rb);
        astoreG(gring + gb2, rb);
      } else {
        astoreL(ring + lb + q, rb);
        astoreG(gring + gb + q, rb);
      }
      if (MODE == 2) {
        if (l == kLanes - 1 && s == kN + kLanes - 1) out[0] = r * kLn2;  // R[4096,4096]
      }
    }

    // ---- issue polls for group g+2 into the buffer just consumed ----
    if (MODE != 2) {
      int pe = (g + 2) * kG;
      if (pe > kRS - kG) pe = kRS - kG;                  // pad (sentinel, unused)
      if (consG) {
#pragma unroll
        for (int q = 0; q < kG; ++q) c[ri][q] = aloadG(gin + pe + q);
      } else {
        const int pb = dummy ? kLBig : (pollIdx + pe);
#pragma unroll
        for (int q = 0; q < kG; ++q) c[ri][q] = aloadL(ring + pb + q);
      }
    }

    // ---- Et prefetch for g+4 ----
    {
      int ge = g + 4;
      if (ge > kGroups - 1) ge = kGroups - 1;
      e4[ei] = EtL[(size_t)ge * 64];
    }

    // ---- fold every 4 groups (w <= 3^32, fp32-safe) ----
    if ((g & 3) == 3) {
      mp  += LOG2F(wp);  wp  = 1.0f;
      mdm += LOG2F(wdm); wdm = 1.0f;
    }
  }
}

__global__ __launch_bounds__(kWaves * kLanes) void sdtw_dp(const uint4* __restrict__ Et,
                                                           u32* __restrict__ gring,
                                                           float* __restrict__ out) {
  const int tid = threadIdx.x;
  const int v = tid >> 6, l = tid & 63;
  const int b = blockIdx.x;
  const int gw = b * kWaves + v;                // global wave/band id 0..63

  __shared__ u32 ring[kLdsTot];
  for (int i = tid; i < 3 * kRS; i += kWaves * kLanes) ring[i] = kSent;
  if (tid < kG) ring[kLBig + tid] = __float_as_uint(kBigP);
  __syncthreads();

  const uint4* EtL = Et + (size_t)gw * kGroups * 64 + l;
  const bool consG = (v == 0) && (b > 0);
  const bool dummy = (v == 0) && (b == 0);
  const bool selL  = (v < kWaves - 1) && (l == kLanes - 1);
  const bool selG  = (v == kWaves - 1) && (b < kBlocks - 1) && (l == kLanes - 1);
  const int  pollIdx = (v > 0) ? (v - 1) * kRS : 0;
  const u32* gin = gring + (size_t)(b > 0 ? b - 1 : 0) * kRS;

  // state pairs: left (mp,wp), diag (mdm,wdm); R' = m - log2(w)
  float mp  = kBigP, wp  = 1.0f;
  float mdm = (gw == 0 && l == 0) ? 0.0f : kBigP;
  float wdm = 1.0f;

  u32 c[2][kG];
  uint4 e4[4];
#pragma unroll
  for (int ph = 0; ph < 4; ++ph) e4[ph] = EtL[(size_t)ph * 64];
#pragma unroll
  for (int ri = 0; ri < 2; ++ri) {
    if (consG) {
#pragma unroll
      for (int q = 0; q < kG; ++q) c[ri][q] = aloadG(gin + ri * kG + q);
    } else {
      const int pb = dummy ? kLBig : (pollIdx + ri * kG);
#pragma unroll
      for (int q = 0; q < kG; ++q) c[ri][q] = aloadL(ring + pb + q);
    }
  }

  run<0>(0,   8,       l, v, b, gw, EtL, ring, gring, consG, dummy, selL, selG,
         pollIdx, gin, mp, wp, mdm, wdm, c, e4, out);
  run<1>(8,   512,     l, v, b, gw, EtL, ring, gring, consG, dummy, selL, selG,
         pollIdx, gin, mp, wp, mdm, wdm, c, e4, out);
  run<2>(512, kGroups, l, v, b, gw, EtL, ring, gring, consG, dummy, selL, selG,
         pollIdx, gin, mp, wp, mdm, wdm, c, e4, out);
}

extern "C" void kernel_launch(void* const* d_in, const int* in_sizes, int n_in,
                              void* d_out, int out_size, void* d_ws, size_t ws_size,
                              hipStream_t stream) {
  const float* A = (const float*)d_in[0];
  const float* B = (const float*)d_in[1];
  float* out = (float*)d_out;

  u32* gring = (u32*)d_ws;
  uint4* Et = (uint4*)(gring + kGRingEnd);
  // ws: 65656*4 B rings/trash + 34.1 MB Et ~= 34.3 MB (fits; R2 proved 35.1 MB)

  sdtw_prep<<<dim3(kGroups / 4, 64), 256, 0, stream>>>(A, B, Et, gring);
  sdtw_dp<<<kBlocks, kWaves * kLanes, 0, stream>>>(Et, gring, out);
}